// Round 1
// baseline (5889.260 us; speedup 1.0000x reference)
//
#include <hip/hip_runtime.h>
#include <math.h>

#define HEADS1 4
#define HID 64
#define LSTM_H 32
#define IN_F 128
#define T_STEPS 50
#define NEG_SLOPE 0.2f
#define EPS_A 1e-16f

// ---------- helpers ----------
__device__ __forceinline__ float sigf(float x) { return 1.0f / (1.0f + __expf(-x)); }
__device__ __forceinline__ float tanhfast(float x) {
    float e = __expf(2.0f * x);
    return 1.0f - 2.0f / (e + 1.0f);
}
__device__ __forceinline__ void atomicMaxF(float* addr, float v) {
    if (v >= 0.0f) atomicMax((int*)addr, __float_as_int(v));
    else atomicMin((unsigned int*)addr, __float_as_uint(v));
}

// ---------- simple LDS-tiled f32 GEMM: C[M,NC] = A[M,K] @ B[K,NC] ----------
template <int K, int NC, int BM>
__global__ void gemm_kernel(const float* __restrict__ A, const float* __restrict__ B,
                            float* __restrict__ C, int M) {
    __shared__ float As[BM * K];
    const int row0 = blockIdx.x * BM;
    for (int idx = threadIdx.x; idx < BM * K; idx += 256) {
        int r = idx / K, k = idx - r * K;
        int row = row0 + r;
        As[idx] = (row < M) ? A[(size_t)row * K + k] : 0.0f;
    }
    __syncthreads();
    const int RPT = BM * NC / 256;   // rows per thread
    const int RSTRIDE = 256 / NC;
    const int col = threadIdx.x % NC;
    const int r0 = threadIdx.x / NC;
    float acc[RPT];
#pragma unroll
    for (int r = 0; r < RPT; r++) acc[r] = 0.0f;
    for (int k = 0; k < K; k += 4) {
#pragma unroll
        for (int kk = 0; kk < 4; kk++) {
            float b = B[(size_t)(k + kk) * NC + col];
#pragma unroll
            for (int r = 0; r < RPT; r++)
                acc[r] += As[(r0 + r * RSTRIDE) * K + k + kk] * b;
        }
    }
#pragma unroll
    for (int r = 0; r < RPT; r++) {
        int row = row0 + r0 + r * RSTRIDE;
        if (row < M) C[(size_t)row * NC + col] = acc[r];
    }
}

// ---------- attention scores: one thread per (node*H + h), dot over 64 ----------
__global__ void att_scores(const float* __restrict__ h, const float* __restrict__ att_s,
                           const float* __restrict__ att_d, float* __restrict__ as_,
                           float* __restrict__ ad_, int NH, int Hmask) {
    int i = blockIdx.x * blockDim.x + threadIdx.x;
    if (i >= NH) return;
    int hh = i & Hmask;
    const float* row = h + (size_t)i * HID;
    float s = 0.0f, d = 0.0f;
#pragma unroll 8
    for (int c = 0; c < HID; c++) {
        float v = row[c];
        s += v * att_s[hh * HID + c];
        d += v * att_d[hh * HID + c];
    }
    as_[i] = s;
    ad_[i] = d;
}

__global__ void init_md(float* __restrict__ m, float* __restrict__ d, int n) {
    int i = blockIdx.x * blockDim.x + threadIdx.x;
    if (i < n) { m[i] = -INFINITY; d[i] = 0.0f; }
}

// ---------- edge pass 1: segment max ----------
template <int H>
__global__ void edge_max(const int* __restrict__ srcs, const int* __restrict__ dsts,
                         int E, int ET, const float* __restrict__ as_,
                         const float* __restrict__ ad_, float* __restrict__ m) {
    int e = blockIdx.x * blockDim.x + threadIdx.x;
    if (e >= ET) return;
    int s = (e < E) ? srcs[e] : (e - E);
    int d = (e < E) ? dsts[e] : (e - E);
#pragma unroll
    for (int h = 0; h < H; h++) {
        float v = as_[s * H + h] + ad_[d * H + h];
        v = (v > 0.0f) ? v : NEG_SLOPE * v;
        atomicMaxF(&m[d * H + h], v);
    }
}

// ---------- edge pass 2: e = exp(leaky - m[dst]); denom += e ----------
template <int H>
__global__ void edge_exp(const int* __restrict__ srcs, const int* __restrict__ dsts,
                         int E, int ET, const float* __restrict__ as_,
                         const float* __restrict__ ad_, const float* __restrict__ m,
                         float* __restrict__ dsum, float* __restrict__ ev) {
    int e = blockIdx.x * blockDim.x + threadIdx.x;
    if (e >= ET) return;
    int s = (e < E) ? srcs[e] : (e - E);
    int d = (e < E) ? dsts[e] : (e - E);
#pragma unroll
    for (int h = 0; h < H; h++) {
        float v = as_[s * H + h] + ad_[d * H + h];
        v = (v > 0.0f) ? v : NEG_SLOPE * v;
        float x = __expf(v - m[d * H + h]);
        ev[e * H + h] = x;
        atomicAdd(&dsum[d * H + h], x);
    }
}

// ---------- edge pass 3 (layer 1, H=4, C=64): one block per edge ----------
__global__ void edge_agg4(const int* __restrict__ srcs, const int* __restrict__ dsts,
                          int E, const float* __restrict__ ev, const float* __restrict__ dsum,
                          const float* __restrict__ hfeat, float* __restrict__ g) {
    int e = blockIdx.x;
    int t = threadIdx.x;  // 0..255 = head*64 + c
    int s = (e < E) ? srcs[e] : (e - E);
    int d = (e < E) ? dsts[e] : (e - E);
    int h = t >> 6;
    float alpha = ev[e * 4 + h] / (dsum[d * 4 + h] + EPS_A);
    atomicAdd(&g[(size_t)d * 256 + t], hfeat[(size_t)s * 256 + t] * alpha);
}

// ---------- edge pass 3 (layer 2, H=1, C=64): 4 edges per block ----------
__global__ void edge_agg1(const int* __restrict__ srcs, const int* __restrict__ dsts,
                          int E, int ET, const float* __restrict__ ev,
                          const float* __restrict__ dsum, const float* __restrict__ hfeat,
                          float* __restrict__ g) {
    int idx = blockIdx.x * blockDim.x + threadIdx.x;
    int e = idx >> 6;
    int c = idx & 63;
    if (e >= ET) return;
    int s = (e < E) ? srcs[e] : (e - E);
    int d = (e < E) ? dsts[e] : (e - E);
    float alpha = ev[e] / (dsum[d] + EPS_A);
    atomicAdd(&g[(size_t)d * 64 + c], hfeat[(size_t)s * 64 + c] * alpha);
}

// ---------- epilogues ----------
__global__ void epilogue_elu_bias(float* __restrict__ g, const float* __restrict__ bias, int n) {
    int i = blockIdx.x * blockDim.x + threadIdx.x;
    if (i >= n) return;
    float v = g[i] + bias[i & 255];
    g[i] = (v > 0.0f) ? v : (__expf(v) - 1.0f);
}
__global__ void epilogue_bias(float* __restrict__ g, const float* __restrict__ bias, int n) {
    int i = blockIdx.x * blockDim.x + threadIdx.x;
    if (i >= n) return;
    g[i] = g[i] + bias[i & 63];
}

// ---------- LSTM: one thread per node, weights via wave-uniform scalar loads ----------
__global__ void lstm_kernel(const float* __restrict__ seq, const float* __restrict__ Wih,
                            const float* __restrict__ Whh, const float* __restrict__ bih,
                            const float* __restrict__ bhh, float* __restrict__ t_out, int N) {
    int n = blockIdx.x * blockDim.x + threadIdx.x;
    if (n >= N) return;
    float h[LSTM_H], c[LSTM_H], hn[LSTM_H];
#pragma unroll
    for (int j = 0; j < LSTM_H; j++) { h[j] = 0.0f; c[j] = 0.0f; }
    const float* s = seq + (size_t)n * (T_STEPS * 3);
    for (int t = 0; t < T_STEPS; t++) {
        float x0 = s[t * 3 + 0], x1 = s[t * 3 + 1], x2 = s[t * 3 + 2];
#pragma unroll
        for (int j = 0; j < LSTM_H; j++) {
            float zi = bih[j] + bhh[j] + Wih[j * 3] * x0 + Wih[j * 3 + 1] * x1 + Wih[j * 3 + 2] * x2;
            float zf = bih[32 + j] + bhh[32 + j] + Wih[(32 + j) * 3] * x0 + Wih[(32 + j) * 3 + 1] * x1 + Wih[(32 + j) * 3 + 2] * x2;
            float zg = bih[64 + j] + bhh[64 + j] + Wih[(64 + j) * 3] * x0 + Wih[(64 + j) * 3 + 1] * x1 + Wih[(64 + j) * 3 + 2] * x2;
            float zo = bih[96 + j] + bhh[96 + j] + Wih[(96 + j) * 3] * x0 + Wih[(96 + j) * 3 + 1] * x1 + Wih[(96 + j) * 3 + 2] * x2;
#pragma unroll
            for (int k = 0; k < LSTM_H; k++) {
                zi += Whh[j * 32 + k] * h[k];
                zf += Whh[(32 + j) * 32 + k] * h[k];
                zg += Whh[(64 + j) * 32 + k] * h[k];
                zo += Whh[(96 + j) * 32 + k] * h[k];
            }
            float ig = sigf(zi), fg = sigf(zf), gg = tanhfast(zg), og = sigf(zo);
            c[j] = fg * c[j] + ig * gg;
            hn[j] = og * tanhfast(c[j]);
        }
#pragma unroll
        for (int j = 0; j < LSTM_H; j++) h[j] = hn[j];
    }
#pragma unroll
    for (int j = 0; j < LSTM_H; j++) t_out[(size_t)n * LSTM_H + j] = h[j];
}

// ---------- fusion MLP: one wave (64 lanes) per node ----------
__global__ void fusion_kernel(const float* __restrict__ g2, const float* __restrict__ tt,
                              const float* __restrict__ Wf1, const float* __restrict__ bf1,
                              const float* __restrict__ Wf2, const float* __restrict__ bf2,
                              float* __restrict__ out, int N) {
    int wave = threadIdx.x >> 6;
    int lane = threadIdx.x & 63;
    int n = blockIdx.x * 4 + wave;
    if (n >= N) return;
    const float* gn = g2 + (size_t)n * 64;
    const float* tn = tt + (size_t)n * 32;
    float acc = bf1[lane];
#pragma unroll 8
    for (int k = 0; k < 64; k++) acc += gn[k] * Wf1[k * 64 + lane];
#pragma unroll 8
    for (int k = 0; k < 32; k++) acc += tn[k] * Wf1[(64 + k) * 64 + lane];
    acc = fmaxf(acc, 0.0f);
    float o0 = acc * Wf2[lane * 2 + 0];
    float o1 = acc * Wf2[lane * 2 + 1];
#pragma unroll
    for (int mk = 32; mk >= 1; mk >>= 1) {
        o0 += __shfl_xor(o0, mk);
        o1 += __shfl_xor(o1, mk);
    }
    if (lane == 0) {
        out[(size_t)n * 2 + 0] = o0 + bf2[0];
        out[(size_t)n * 2 + 1] = o1 + bf2[1];
    }
}

extern "C" void kernel_launch(void* const* d_in, const int* in_sizes, int n_in,
                              void* d_out, int out_size, void* d_ws, size_t ws_size,
                              hipStream_t stream) {
    const float* x      = (const float*)d_in[0];
    const int*   eidx   = (const int*)d_in[1];
    const float* seq    = (const float*)d_in[2];
    const float* W1     = (const float*)d_in[3];
    const float* att_s1 = (const float*)d_in[4];
    const float* att_d1 = (const float*)d_in[5];
    const float* bias1  = (const float*)d_in[6];
    const float* W2     = (const float*)d_in[7];
    const float* att_s2 = (const float*)d_in[8];
    const float* att_d2 = (const float*)d_in[9];
    const float* bias2  = (const float*)d_in[10];
    const float* Wih    = (const float*)d_in[11];
    const float* Whh    = (const float*)d_in[12];
    const float* bih    = (const float*)d_in[13];
    const float* bhh    = (const float*)d_in[14];
    const float* Wf1    = (const float*)d_in[15];
    const float* bf1    = (const float*)d_in[16];
    const float* Wf2    = (const float*)d_in[17];
    const float* bf2    = (const float*)d_in[18];
    float* out = (float*)d_out;

    const int N  = in_sizes[0] / IN_F;   // 50000
    const int E  = in_sizes[1] / 2;      // 800000
    const int ET = E + N;                // with self-loops
    const int* srcs = eidx;
    const int* dsts = eidx + E;

    // workspace layout (floats)
    float* W   = (float*)d_ws;
    float* h1  = W;                                // N*256
    float* g1  = h1 + (size_t)N * 256;             // N*256
    float* as1 = g1 + (size_t)N * 256;             // N*4
    float* ad1 = as1 + (size_t)N * 4;              // N*4
    float* m1  = ad1 + (size_t)N * 4;              // N*4
    float* dn1 = m1 + (size_t)N * 4;               // N*4
    float* ev1 = dn1 + (size_t)N * 4;              // ET*4
    // layer-2 / LSTM aliases into the (by-then free) h1 region & layer-1 scalars
    float* h2  = h1;                               // N*64
    float* g2  = h1 + (size_t)N * 64;              // N*64
    float* tt  = h1 + (size_t)N * 128;             // N*32
    float* as2 = as1; float* ad2 = ad1; float* m2 = m1; float* dn2 = dn1; float* ev2 = ev1;

    dim3 blk(256);

    // ---- GAT layer 1 ----
    gemm_kernel<128, 256, 16><<<(N + 15) / 16, blk, 0, stream>>>(x, W1, h1, N);
    att_scores<<<(N * 4 + 255) / 256, blk, 0, stream>>>(h1, att_s1, att_d1, as1, ad1, N * 4, 3);
    init_md<<<(N * 4 + 255) / 256, blk, 0, stream>>>(m1, dn1, N * 4);
    hipMemsetAsync(g1, 0, (size_t)N * 256 * sizeof(float), stream);
    edge_max<4><<<(ET + 255) / 256, blk, 0, stream>>>(srcs, dsts, E, ET, as1, ad1, m1);
    edge_exp<4><<<(ET + 255) / 256, blk, 0, stream>>>(srcs, dsts, E, ET, as1, ad1, m1, dn1, ev1);
    edge_agg4<<<ET, blk, 0, stream>>>(srcs, dsts, E, ev1, dn1, h1, g1);
    epilogue_elu_bias<<<(N * 256 + 255) / 256, blk, 0, stream>>>(g1, bias1, N * 256);

    // ---- GAT layer 2 ----
    gemm_kernel<256, 64, 16><<<(N + 15) / 16, blk, 0, stream>>>(g1, W2, h2, N);
    att_scores<<<(N + 255) / 256, blk, 0, stream>>>(h2, att_s2, att_d2, as2, ad2, N, 0);
    init_md<<<(N + 255) / 256, blk, 0, stream>>>(m2, dn2, N);
    hipMemsetAsync(g2, 0, (size_t)N * 64 * sizeof(float), stream);
    edge_max<1><<<(ET + 255) / 256, blk, 0, stream>>>(srcs, dsts, E, ET, as2, ad2, m2);
    edge_exp<1><<<(ET + 255) / 256, blk, 0, stream>>>(srcs, dsts, E, ET, as2, ad2, m2, dn2, ev2);
    edge_agg1<<<((size_t)ET * 64 + 255) / 256, blk, 0, stream>>>(srcs, dsts, E, ET, ev2, dn2, h2, g2);
    epilogue_bias<<<(N * 64 + 255) / 256, blk, 0, stream>>>(g2, bias2, N * 64);

    // ---- LSTM ----
    lstm_kernel<<<(N + 255) / 256, blk, 0, stream>>>(seq, Wih, Whh, bih, bhh, tt, N);

    // ---- fusion MLP ----
    fusion_kernel<<<(N + 3) / 4, blk, 0, stream>>>(g2, tt, Wf1, bf1, Wf2, bf2, out, N);
}

// Round 2
// 2447.994 us; speedup vs baseline: 2.4057x; 2.4057x over previous
//
#include <hip/hip_runtime.h>
#include <math.h>

#define HEADS1 4
#define HID 64
#define LSTM_H 32
#define IN_F 128
#define T_STEPS 50
#define NEG_SLOPE 0.2f
#define EPS_A 1e-16f

// ---------- helpers ----------
__device__ __forceinline__ float sigf(float x) { return 1.0f / (1.0f + __expf(-x)); }
__device__ __forceinline__ float tanhfast(float x) {
    float e = __expf(2.0f * x);
    return 1.0f - 2.0f / (e + 1.0f);
}
__device__ __forceinline__ void atomicMaxF(float* addr, float v) {
    if (v >= 0.0f) atomicMax((int*)addr, __float_as_int(v));
    else atomicMin((unsigned int*)addr, __float_as_uint(v));
}

// ---------- simple LDS-tiled f32 GEMM: C[M,NC] = A[M,K] @ B[K,NC] ----------
template <int K, int NC, int BM>
__global__ void gemm_kernel(const float* __restrict__ A, const float* __restrict__ B,
                            float* __restrict__ C, int M) {
    __shared__ float As[BM * K];
    const int row0 = blockIdx.x * BM;
    for (int idx = threadIdx.x; idx < BM * K; idx += 256) {
        int r = idx / K, k = idx - r * K;
        int row = row0 + r;
        As[idx] = (row < M) ? A[(size_t)row * K + k] : 0.0f;
    }
    __syncthreads();
    const int RPT = BM * NC / 256;   // rows per thread
    const int RSTRIDE = 256 / NC;
    const int col = threadIdx.x % NC;
    const int r0 = threadIdx.x / NC;
    float acc[RPT];
#pragma unroll
    for (int r = 0; r < RPT; r++) acc[r] = 0.0f;
    for (int k = 0; k < K; k += 4) {
#pragma unroll
        for (int kk = 0; kk < 4; kk++) {
            float b = B[(size_t)(k + kk) * NC + col];
#pragma unroll
            for (int r = 0; r < RPT; r++)
                acc[r] += As[(r0 + r * RSTRIDE) * K + k + kk] * b;
        }
    }
#pragma unroll
    for (int r = 0; r < RPT; r++) {
        int row = row0 + r0 + r * RSTRIDE;
        if (row < M) C[(size_t)row * NC + col] = acc[r];
    }
}

// ---------- attention scores: one thread per (node*H + h), dot over 64 ----------
__global__ void att_scores(const float* __restrict__ h, const float* __restrict__ att_s,
                           const float* __restrict__ att_d, float* __restrict__ as_,
                           float* __restrict__ ad_, int NH, int Hmask) {
    int i = blockIdx.x * blockDim.x + threadIdx.x;
    if (i >= NH) return;
    int hh = i & Hmask;
    const float* row = h + (size_t)i * HID;
    float s = 0.0f, d = 0.0f;
#pragma unroll 8
    for (int c = 0; c < HID; c++) {
        float v = row[c];
        s += v * att_s[hh * HID + c];
        d += v * att_d[hh * HID + c];
    }
    as_[i] = s;
    ad_[i] = d;
}

__global__ void init_md(float* __restrict__ m, float* __restrict__ d, int n) {
    int i = blockIdx.x * blockDim.x + threadIdx.x;
    if (i < n) { m[i] = -INFINITY; d[i] = 0.0f; }
}

// ---------- edge pass 1: segment max ----------
template <int H>
__global__ void edge_max(const int* __restrict__ srcs, const int* __restrict__ dsts,
                         int E, int ET, const float* __restrict__ as_,
                         const float* __restrict__ ad_, float* __restrict__ m) {
    int e = blockIdx.x * blockDim.x + threadIdx.x;
    if (e >= ET) return;
    int s = (e < E) ? srcs[e] : (e - E);
    int d = (e < E) ? dsts[e] : (e - E);
#pragma unroll
    for (int h = 0; h < H; h++) {
        float v = as_[s * H + h] + ad_[d * H + h];
        v = (v > 0.0f) ? v : NEG_SLOPE * v;
        atomicMaxF(&m[d * H + h], v);
    }
}

// ---------- edge pass 2: e = exp(leaky - m[dst]); denom += e ----------
template <int H>
__global__ void edge_exp(const int* __restrict__ srcs, const int* __restrict__ dsts,
                         int E, int ET, const float* __restrict__ as_,
                         const float* __restrict__ ad_, const float* __restrict__ m,
                         float* __restrict__ dsum, float* __restrict__ ev) {
    int e = blockIdx.x * blockDim.x + threadIdx.x;
    if (e >= ET) return;
    int s = (e < E) ? srcs[e] : (e - E);
    int d = (e < E) ? dsts[e] : (e - E);
#pragma unroll
    for (int h = 0; h < H; h++) {
        float v = as_[s * H + h] + ad_[d * H + h];
        v = (v > 0.0f) ? v : NEG_SLOPE * v;
        float x = __expf(v - m[d * H + h]);
        ev[e * H + h] = x;
        atomicAdd(&dsum[d * H + h], x);
    }
}

// ---------- edge pass 3 (layer 1, H=4, C=64): one block per edge ----------
__global__ void edge_agg4(const int* __restrict__ srcs, const int* __restrict__ dsts,
                          int E, const float* __restrict__ ev, const float* __restrict__ dsum,
                          const float* __restrict__ hfeat, float* __restrict__ g) {
    int e = blockIdx.x;
    int t = threadIdx.x;  // 0..255 = head*64 + c
    int s = (e < E) ? srcs[e] : (e - E);
    int d = (e < E) ? dsts[e] : (e - E);
    int h = t >> 6;
    float alpha = ev[e * 4 + h] / (dsum[d * 4 + h] + EPS_A);
    atomicAdd(&g[(size_t)d * 256 + t], hfeat[(size_t)s * 256 + t] * alpha);
}

// ---------- edge pass 3 (layer 2, H=1, C=64): 4 edges per block ----------
__global__ void edge_agg1(const int* __restrict__ srcs, const int* __restrict__ dsts,
                          int E, int ET, const float* __restrict__ ev,
                          const float* __restrict__ dsum, const float* __restrict__ hfeat,
                          float* __restrict__ g) {
    int idx = blockIdx.x * blockDim.x + threadIdx.x;
    int e = idx >> 6;
    int c = idx & 63;
    if (e >= ET) return;
    int s = (e < E) ? srcs[e] : (e - E);
    int d = (e < E) ? dsts[e] : (e - E);
    float alpha = ev[e] / (dsum[d] + EPS_A);
    atomicAdd(&g[(size_t)d * 64 + c], hfeat[(size_t)s * 64 + c] * alpha);
}

// ---------- epilogues ----------
__global__ void epilogue_elu_bias(float* __restrict__ g, const float* __restrict__ bias, int n) {
    int i = blockIdx.x * blockDim.x + threadIdx.x;
    if (i >= n) return;
    float v = g[i] + bias[i & 255];
    g[i] = (v > 0.0f) ? v : (__expf(v) - 1.0f);
}
__global__ void epilogue_bias(float* __restrict__ g, const float* __restrict__ bias, int n) {
    int i = blockIdx.x * blockDim.x + threadIdx.x;
    if (i >= n) return;
    g[i] = g[i] + bias[i & 63];
}

// ---------- LSTM v2: 256 threads = 8 nodes x 32 hidden units ----------
// Whh gate-rows live in VGPRs (128 floats/thread, loaded once); h shared via
// double-buffered LDS (broadcast float4 reads); sequence staged to LDS coalesced.
#define NPB 8   // nodes per block
__global__ __launch_bounds__(256, 3)
void lstm_kernel(const float* __restrict__ seq, const float* __restrict__ Wih,
                 const float* __restrict__ Whh, const float* __restrict__ bih,
                 const float* __restrict__ bhh, float* __restrict__ t_out, int N) {
    __shared__ float s_seq[NPB * T_STEPS * 3];   // 4800 B
    __shared__ float s_h[2][NPB][LSTM_H];        // 2 KB, double-buffered

    const int local = threadIdx.x >> 5;   // node within block
    const int j     = threadIdx.x & 31;   // hidden unit
    const int node0 = blockIdx.x * NPB;
    const int node  = node0 + local;

    // stage sequences: NPB*150 contiguous floats
    {
        const float* src = seq + (size_t)node0 * (T_STEPS * 3);
        const int total = NPB * T_STEPS * 3;
        for (int i = threadIdx.x; i < total; i += 256) {
            int gn = node0 + i / (T_STEPS * 3);
            s_seq[i] = (gn < N) ? src[i] : 0.0f;
        }
    }

    // per-thread weights in registers: rows {j, 32+j, 64+j, 96+j} of Whh
    float w[4][LSTM_H];
#pragma unroll
    for (int g = 0; g < 4; g++) {
        const float4* rp = (const float4*)(Whh + (size_t)(g * 32 + j) * 32);
#pragma unroll
        for (int q = 0; q < 8; q++) {
            float4 v = rp[q];
            w[g][q * 4 + 0] = v.x; w[g][q * 4 + 1] = v.y;
            w[g][q * 4 + 2] = v.z; w[g][q * 4 + 3] = v.w;
        }
    }
    float wi[4][3], bz[4];
#pragma unroll
    for (int g = 0; g < 4; g++) {
        int r = g * 32 + j;
        wi[g][0] = Wih[r * 3 + 0];
        wi[g][1] = Wih[r * 3 + 1];
        wi[g][2] = Wih[r * 3 + 2];
        bz[g] = bih[r] + bhh[r];
    }

    float c = 0.0f, hn = 0.0f;
    s_h[0][local][j] = 0.0f;
    __syncthreads();

    for (int t = 0; t < T_STEPS; t++) {
        const int cur = t & 1, nxt = cur ^ 1;
        float x0 = s_seq[local * 150 + t * 3 + 0];
        float x1 = s_seq[local * 150 + t * 3 + 1];
        float x2 = s_seq[local * 150 + t * 3 + 2];
        float z[4];
#pragma unroll
        for (int g = 0; g < 4; g++)
            z[g] = bz[g] + wi[g][0] * x0 + wi[g][1] * x1 + wi[g][2] * x2;
        const float4* hp = (const float4*)s_h[cur][local];
#pragma unroll
        for (int q = 0; q < 8; q++) {
            float4 hv = hp[q];
#pragma unroll
            for (int g = 0; g < 4; g++) {
                z[g] += w[g][q * 4 + 0] * hv.x + w[g][q * 4 + 1] * hv.y +
                        w[g][q * 4 + 2] * hv.z + w[g][q * 4 + 3] * hv.w;
            }
        }
        float ig = sigf(z[0]), fg = sigf(z[1]);
        float gg = tanhfast(z[2]), og = sigf(z[3]);
        c = fg * c + ig * gg;
        hn = og * tanhfast(c);
        s_h[nxt][local][j] = hn;
        __syncthreads();
    }

    if (node < N) t_out[(size_t)node0 * LSTM_H + threadIdx.x] = hn;
}

// ---------- fusion MLP: one wave (64 lanes) per node ----------
__global__ void fusion_kernel(const float* __restrict__ g2, const float* __restrict__ tt,
                              const float* __restrict__ Wf1, const float* __restrict__ bf1,
                              const float* __restrict__ Wf2, const float* __restrict__ bf2,
                              float* __restrict__ out, int N) {
    int wave = threadIdx.x >> 6;
    int lane = threadIdx.x & 63;
    int n = blockIdx.x * 4 + wave;
    if (n >= N) return;
    const float* gn = g2 + (size_t)n * 64;
    const float* tn = tt + (size_t)n * 32;
    float acc = bf1[lane];
#pragma unroll 8
    for (int k = 0; k < 64; k++) acc += gn[k] * Wf1[k * 64 + lane];
#pragma unroll 8
    for (int k = 0; k < 32; k++) acc += tn[k] * Wf1[(64 + k) * 64 + lane];
    acc = fmaxf(acc, 0.0f);
    float o0 = acc * Wf2[lane * 2 + 0];
    float o1 = acc * Wf2[lane * 2 + 1];
#pragma unroll
    for (int mk = 32; mk >= 1; mk >>= 1) {
        o0 += __shfl_xor(o0, mk);
        o1 += __shfl_xor(o1, mk);
    }
    if (lane == 0) {
        out[(size_t)n * 2 + 0] = o0 + bf2[0];
        out[(size_t)n * 2 + 1] = o1 + bf2[1];
    }
}

extern "C" void kernel_launch(void* const* d_in, const int* in_sizes, int n_in,
                              void* d_out, int out_size, void* d_ws, size_t ws_size,
                              hipStream_t stream) {
    const float* x      = (const float*)d_in[0];
    const int*   eidx   = (const int*)d_in[1];
    const float* seq    = (const float*)d_in[2];
    const float* W1     = (const float*)d_in[3];
    const float* att_s1 = (const float*)d_in[4];
    const float* att_d1 = (const float*)d_in[5];
    const float* bias1  = (const float*)d_in[6];
    const float* W2     = (const float*)d_in[7];
    const float* att_s2 = (const float*)d_in[8];
    const float* att_d2 = (const float*)d_in[9];
    const float* bias2  = (const float*)d_in[10];
    const float* Wih    = (const float*)d_in[11];
    const float* Whh    = (const float*)d_in[12];
    const float* bih    = (const float*)d_in[13];
    const float* bhh    = (const float*)d_in[14];
    const float* Wf1    = (const float*)d_in[15];
    const float* bf1    = (const float*)d_in[16];
    const float* Wf2    = (const float*)d_in[17];
    const float* bf2    = (const float*)d_in[18];
    float* out = (float*)d_out;

    const int N  = in_sizes[0] / IN_F;   // 50000
    const int E  = in_sizes[1] / 2;      // 800000
    const int ET = E + N;                // with self-loops
    const int* srcs = eidx;
    const int* dsts = eidx + E;

    // workspace layout (floats)
    float* h1  = (float*)d_ws;                     // N*256
    float* g1  = h1 + (size_t)N * 256;             // N*256
    float* as1 = g1 + (size_t)N * 256;             // N*4
    float* ad1 = as1 + (size_t)N * 4;              // N*4
    float* m1  = ad1 + (size_t)N * 4;              // N*4
    float* dn1 = m1 + (size_t)N * 4;               // N*4
    float* ev1 = dn1 + (size_t)N * 4;              // ET*4
    // layer-2 / LSTM aliases into the (by-then free) h1 region
    float* h2  = h1;                               // N*64
    float* g2  = h1 + (size_t)N * 64;              // N*64
    float* tt  = h1 + (size_t)N * 128;             // N*32
    float* as2 = as1; float* ad2 = ad1; float* m2 = m1; float* dn2 = dn1; float* ev2 = ev1;

    dim3 blk(256);

    // ---- GAT layer 1 ----
    gemm_kernel<128, 256, 16><<<(N + 15) / 16, blk, 0, stream>>>(x, W1, h1, N);
    att_scores<<<(N * 4 + 255) / 256, blk, 0, stream>>>(h1, att_s1, att_d1, as1, ad1, N * 4, 3);
    init_md<<<(N * 4 + 255) / 256, blk, 0, stream>>>(m1, dn1, N * 4);
    hipMemsetAsync(g1, 0, (size_t)N * 256 * sizeof(float), stream);
    edge_max<4><<<(ET + 255) / 256, blk, 0, stream>>>(srcs, dsts, E, ET, as1, ad1, m1);
    edge_exp<4><<<(ET + 255) / 256, blk, 0, stream>>>(srcs, dsts, E, ET, as1, ad1, m1, dn1, ev1);
    edge_agg4<<<ET, blk, 0, stream>>>(srcs, dsts, E, ev1, dn1, h1, g1);
    epilogue_elu_bias<<<(N * 256 + 255) / 256, blk, 0, stream>>>(g1, bias1, N * 256);

    // ---- GAT layer 2 ----
    gemm_kernel<256, 64, 16><<<(N + 15) / 16, blk, 0, stream>>>(g1, W2, h2, N);
    att_scores<<<(N + 255) / 256, blk, 0, stream>>>(h2, att_s2, att_d2, as2, ad2, N, 0);
    init_md<<<(N + 255) / 256, blk, 0, stream>>>(m2, dn2, N);
    hipMemsetAsync(g2, 0, (size_t)N * 64 * sizeof(float), stream);
    edge_max<1><<<(ET + 255) / 256, blk, 0, stream>>>(srcs, dsts, E, ET, as2, ad2, m2);
    edge_exp<1><<<(ET + 255) / 256, blk, 0, stream>>>(srcs, dsts, E, ET, as2, ad2, m2, dn2, ev2);
    edge_agg1<<<((size_t)ET * 64 + 255) / 256, blk, 0, stream>>>(srcs, dsts, E, ET, ev2, dn2, h2, g2);
    epilogue_bias<<<(N * 64 + 255) / 256, blk, 0, stream>>>(g2, bias2, N * 64);

    // ---- LSTM ----
    lstm_kernel<<<(N + NPB - 1) / NPB, blk, 0, stream>>>(seq, Wih, Whh, bih, bhh, tt, N);

    // ---- fusion MLP ----
    fusion_kernel<<<(N + 3) / 4, blk, 0, stream>>>(g2, tt, Wf1, bf1, Wf2, bf2, out, N);
}

// Round 3
// 1377.446 us; speedup vs baseline: 4.2755x; 1.7772x over previous
//
#include <hip/hip_runtime.h>
#include <math.h>

#define HEADS1 4
#define HID 64
#define LSTM_H 32
#define IN_F 128
#define T_STEPS 50
#define NEG_SLOPE 0.2f
#define EPS_A 1e-16f

// ---------- helpers ----------
__device__ __forceinline__ float sigf(float x) { return 1.0f / (1.0f + __expf(-x)); }
__device__ __forceinline__ float tanhfast(float x) {
    float e = __expf(2.0f * x);
    return 1.0f - 2.0f / (e + 1.0f);
}

// ---------- simple LDS-tiled f32 GEMM: C[M,NC] = A[M,K] @ B[K,NC] ----------
template <int K, int NC, int BM>
__global__ void gemm_kernel(const float* __restrict__ A, const float* __restrict__ B,
                            float* __restrict__ C, int M) {
    __shared__ float As[BM * K];
    const int row0 = blockIdx.x * BM;
    for (int idx = threadIdx.x; idx < BM * K; idx += 256) {
        int r = idx / K, k = idx - r * K;
        int row = row0 + r;
        As[idx] = (row < M) ? A[(size_t)row * K + k] : 0.0f;
    }
    __syncthreads();
    const int RPT = BM * NC / 256;   // rows per thread
    const int RSTRIDE = 256 / NC;
    const int col = threadIdx.x % NC;
    const int r0 = threadIdx.x / NC;
    float acc[RPT];
#pragma unroll
    for (int r = 0; r < RPT; r++) acc[r] = 0.0f;
    for (int k = 0; k < K; k += 4) {
#pragma unroll
        for (int kk = 0; kk < 4; kk++) {
            float b = B[(size_t)(k + kk) * NC + col];
#pragma unroll
            for (int r = 0; r < RPT; r++)
                acc[r] += As[(r0 + r * RSTRIDE) * K + k + kk] * b;
        }
    }
#pragma unroll
    for (int r = 0; r < RPT; r++) {
        int row = row0 + r0 + r * RSTRIDE;
        if (row < M) C[(size_t)row * NC + col] = acc[r];
    }
}

// ---------- attention scores: one thread per (node*H + h), dot over 64 ----------
__global__ void att_scores(const float* __restrict__ h, const float* __restrict__ att_s,
                           const float* __restrict__ att_d, float* __restrict__ as_,
                           float* __restrict__ ad_, int NH, int Hmask) {
    int i = blockIdx.x * blockDim.x + threadIdx.x;
    if (i >= NH) return;
    int hh = i & Hmask;
    const float* row = h + (size_t)i * HID;
    float s = 0.0f, d = 0.0f;
#pragma unroll 8
    for (int c = 0; c < HID; c++) {
        float v = row[c];
        s += v * att_s[hh * HID + c];
        d += v * att_d[hh * HID + c];
    }
    as_[i] = s;
    ad_[i] = d;
}

// ---------- CSR build ----------
__global__ void count_deg(const int* __restrict__ dsts, int E, int ET, int* __restrict__ cnt) {
    int e = blockIdx.x * blockDim.x + threadIdx.x;
    if (e >= ET) return;
    int d = (e < E) ? dsts[e] : (e - E);
    atomicAdd(&cnt[d], 1);
}

// single-block exclusive scan of cnt[0..N) -> rowp[0..N]
__global__ void scan_kernel(const int* __restrict__ cnt, int* __restrict__ rowp, int N) {
    __shared__ int tmp[1024];
    __shared__ int carry_s;
    if (threadIdx.x == 0) carry_s = 0;
    __syncthreads();
    for (int base = 0; base < N; base += 1024) {
        int i = base + threadIdx.x;
        int v = (i < N) ? cnt[i] : 0;
        tmp[threadIdx.x] = v;
        __syncthreads();
        for (int off = 1; off < 1024; off <<= 1) {
            int t = (threadIdx.x >= off) ? tmp[threadIdx.x - off] : 0;
            __syncthreads();
            tmp[threadIdx.x] += t;
            __syncthreads();
        }
        if (i < N) rowp[i] = carry_s + tmp[threadIdx.x] - v;
        __syncthreads();
        if (threadIdx.x == 1023) carry_s += tmp[1023];
        __syncthreads();
    }
    if (threadIdx.x == 0) rowp[N] = carry_s;
}

__global__ void scatter_edges(const int* __restrict__ dsts, int E, int ET,
                              const int* __restrict__ rowp, int* __restrict__ cursor,
                              int* __restrict__ eid) {
    int e = blockIdx.x * blockDim.x + threadIdx.x;
    if (e >= ET) return;
    int d = (e < E) ? dsts[e] : (e - E);
    int pos = atomicAdd(&cursor[d], 1);
    eid[rowp[d] + pos] = e;
}

// ---------- fused per-dst GAT softmax + aggregation ----------
// H=4: block 256 = 1 dst, wave w = head w.  H=1: block 256 = 4 dsts, wave per dst.
template <int H>
__global__ void gat_agg_fused(const int* __restrict__ srcs, int E,
                              const int* __restrict__ rowp, const int* __restrict__ eid,
                              const float* __restrict__ as_, const float* __restrict__ ad_,
                              const float* __restrict__ hfeat, const float* __restrict__ bias,
                              float* __restrict__ g, int N, int do_elu) {
    const int wave = threadIdx.x >> 6;
    const int lane = threadIdx.x & 63;
    int dst, h;
    if (H == 4) { dst = blockIdx.x; h = wave; }
    else        { dst = blockIdx.x * 4 + wave; h = 0; }
    if (dst >= N) return;
    const int start = rowp[dst], end = rowp[dst + 1];
    const float adv = ad_[dst * H + h];

    // pass 1: segment max
    float m = -INFINITY;
    for (int i0 = start; i0 < end; i0 += 64) {
        int i = i0 + lane;
        float v = -INFINITY;
        if (i < end) {
            int e = eid[i];
            int s = (e < E) ? srcs[e] : (e - E);
            float t = as_[s * H + h] + adv;
            v = (t > 0.0f) ? t : NEG_SLOPE * t;
        }
        m = fmaxf(m, v);
    }
#pragma unroll
    for (int mk = 32; mk >= 1; mk >>= 1) m = fmaxf(m, __shfl_xor(m, mk));

    // pass 2: denom
    float dsum = 0.0f;
    for (int i0 = start; i0 < end; i0 += 64) {
        int i = i0 + lane;
        float x = 0.0f;
        if (i < end) {
            int e = eid[i];
            int s = (e < E) ? srcs[e] : (e - E);
            float t = as_[s * H + h] + adv;
            t = (t > 0.0f) ? t : NEG_SLOPE * t;
            x = __expf(t - m);
        }
        dsum += x;
    }
#pragma unroll
    for (int mk = 32; mk >= 1; mk >>= 1) dsum += __shfl_xor(dsum, mk);
    const float inv = 1.0f / (dsum + EPS_A);

    // pass 3: weighted gather-accumulate (lane = channel within head)
    float acc = 0.0f;
    for (int i0 = start; i0 < end; i0 += 64) {
        int cnt = min(64, end - i0);
        int i = i0 + lane;
        float alpha = 0.0f;
        int s = 0;
        if (i < end) {
            int e = eid[i];
            s = (e < E) ? srcs[e] : (e - E);
            float t = as_[s * H + h] + adv;
            t = (t > 0.0f) ? t : NEG_SLOPE * t;
            alpha = __expf(t - m) * inv;
        }
#pragma unroll 4
        for (int k = 0; k < cnt; k++) {
            float a_k = __shfl(alpha, k);
            int   s_k = __shfl(s, k);
            acc += hfeat[(size_t)s_k * (H * 64) + h * 64 + lane] * a_k;
        }
    }
    float r = acc + bias[h * 64 + lane];
    if (do_elu) r = (r > 0.0f) ? r : __expf(r) - 1.0f;
    g[(size_t)dst * (H * 64) + h * 64 + lane] = r;
}

// ---------- LSTM: 256 threads = 8 nodes x 32 hidden units, weights pinned in VGPRs ----------
#define NPB 8   // nodes per block
__global__ __launch_bounds__(256, 2)
void lstm_kernel(const float* __restrict__ seq, const float* __restrict__ Wih,
                 const float* __restrict__ Whh, const float* __restrict__ bih,
                 const float* __restrict__ bhh, float* __restrict__ t_out, int N) {
    __shared__ float s_seq[NPB * T_STEPS * 3];   // 4800 B
    __shared__ float s_h[2][NPB][LSTM_H];        // 2 KB, double-buffered

    const int local = threadIdx.x >> 5;   // node within block
    const int j     = threadIdx.x & 31;   // hidden unit
    const int node0 = blockIdx.x * NPB;
    const int node  = node0 + local;

    // stage sequences: NPB*150 contiguous floats
    {
        const float* src = seq + (size_t)node0 * (T_STEPS * 3);
        const int total = NPB * T_STEPS * 3;
        for (int i = threadIdx.x; i < total; i += 256) {
            int gn = node0 + i / (T_STEPS * 3);
            s_seq[i] = (gn < N) ? src[i] : 0.0f;
        }
    }

    // per-thread weights in registers: rows {j, 32+j, 64+j, 96+j} of Whh
    float w[4][LSTM_H];
#pragma unroll
    for (int g = 0; g < 4; g++) {
        const float4* rp = (const float4*)(Whh + (size_t)(g * 32 + j) * 32);
#pragma unroll
        for (int q = 0; q < 8; q++) {
            float4 v = rp[q];
            w[g][q * 4 + 0] = v.x; w[g][q * 4 + 1] = v.y;
            w[g][q * 4 + 2] = v.z; w[g][q * 4 + 3] = v.w;
        }
    }
    float wi[4][3], bz[4];
#pragma unroll
    for (int g = 0; g < 4; g++) {
        int r = g * 32 + j;
        wi[g][0] = Wih[r * 3 + 0];
        wi[g][1] = Wih[r * 3 + 1];
        wi[g][2] = Wih[r * 3 + 2];
        bz[g] = bih[r] + bhh[r];
    }
    // pin weights in VGPRs: asm "modifies" them, so the compiler cannot
    // re-materialize the loads inside the t-loop (the round-2 VGPR=84 failure)
#pragma unroll
    for (int g = 0; g < 4; g++) {
#pragma unroll
        for (int k = 0; k < LSTM_H; k++) asm volatile("" : "+v"(w[g][k]));
#pragma unroll
        for (int k = 0; k < 3; k++) asm volatile("" : "+v"(wi[g][k]));
        asm volatile("" : "+v"(bz[g]));
    }

    float c = 0.0f, hn = 0.0f;
    s_h[0][local][j] = 0.0f;
    __syncthreads();   // covers s_seq staging + h init

    for (int t = 0; t < T_STEPS; t++) {
        const int cur = t & 1, nxt = cur ^ 1;
        float x0 = s_seq[local * 150 + t * 3 + 0];
        float x1 = s_seq[local * 150 + t * 3 + 1];
        float x2 = s_seq[local * 150 + t * 3 + 2];
        float z[4];
#pragma unroll
        for (int g = 0; g < 4; g++)
            z[g] = bz[g] + wi[g][0] * x0 + wi[g][1] * x1 + wi[g][2] * x2;
        const float4* hp = (const float4*)s_h[cur][local];
#pragma unroll
        for (int q = 0; q < 8; q++) {
            float4 hv = hp[q];
#pragma unroll
            for (int g = 0; g < 4; g++) {
                z[g] += w[g][q * 4 + 0] * hv.x + w[g][q * 4 + 1] * hv.y +
                        w[g][q * 4 + 2] * hv.z + w[g][q * 4 + 3] * hv.w;
            }
        }
        float ig = sigf(z[0]), fg = sigf(z[1]);
        float gg = tanhfast(z[2]), og = sigf(z[3]);
        c = fg * c + ig * gg;
        hn = og * tanhfast(c);
        // producer and consumers of a node's h are within ONE wave -> no
        // __syncthreads needed; wave_barrier stops compiler reordering (free)
        __builtin_amdgcn_wave_barrier();
        s_h[nxt][local][j] = hn;
        __builtin_amdgcn_wave_barrier();
    }

    if (node < N) t_out[(size_t)node0 * LSTM_H + threadIdx.x] = hn;
}

// ---------- fusion MLP: Wf1 staged in LDS, waves grid-stride over nodes ----------
__global__ void fusion_kernel(const float* __restrict__ g2, const float* __restrict__ tt,
                              const float* __restrict__ Wf1, const float* __restrict__ bf1,
                              const float* __restrict__ Wf2, const float* __restrict__ bf2,
                              float* __restrict__ out, int N) {
    __shared__ float sW[96 * 64];
    __shared__ float sb1[64];
    __shared__ float sW2[128];
    for (int i = threadIdx.x; i < 96 * 64; i += 256) sW[i] = Wf1[i];
    if (threadIdx.x < 64) sb1[threadIdx.x] = bf1[threadIdx.x];
    if (threadIdx.x < 128) sW2[threadIdx.x] = Wf2[threadIdx.x];
    __syncthreads();
    const int wave = threadIdx.x >> 6;
    const int lane = threadIdx.x & 63;
    for (int n = blockIdx.x * 4 + wave; n < N; n += gridDim.x * 4) {
        const float* gn = g2 + (size_t)n * 64;
        const float* tn = tt + (size_t)n * 32;
        float acc = sb1[lane];
#pragma unroll 8
        for (int k = 0; k < 64; k++) acc += gn[k] * sW[k * 64 + lane];
#pragma unroll 8
        for (int k = 0; k < 32; k++) acc += tn[k] * sW[(64 + k) * 64 + lane];
        acc = fmaxf(acc, 0.0f);
        float o0 = acc * sW2[lane * 2 + 0];
        float o1 = acc * sW2[lane * 2 + 1];
#pragma unroll
        for (int mk = 32; mk >= 1; mk >>= 1) {
            o0 += __shfl_xor(o0, mk);
            o1 += __shfl_xor(o1, mk);
        }
        if (lane == 0) {
            out[(size_t)n * 2 + 0] = o0 + bf2[0];
            out[(size_t)n * 2 + 1] = o1 + bf2[1];
        }
    }
}

extern "C" void kernel_launch(void* const* d_in, const int* in_sizes, int n_in,
                              void* d_out, int out_size, void* d_ws, size_t ws_size,
                              hipStream_t stream) {
    const float* x      = (const float*)d_in[0];
    const int*   eidx   = (const int*)d_in[1];
    const float* seq    = (const float*)d_in[2];
    const float* W1     = (const float*)d_in[3];
    const float* att_s1 = (const float*)d_in[4];
    const float* att_d1 = (const float*)d_in[5];
    const float* bias1  = (const float*)d_in[6];
    const float* W2     = (const float*)d_in[7];
    const float* att_s2 = (const float*)d_in[8];
    const float* att_d2 = (const float*)d_in[9];
    const float* bias2  = (const float*)d_in[10];
    const float* Wih    = (const float*)d_in[11];
    const float* Whh    = (const float*)d_in[12];
    const float* bih    = (const float*)d_in[13];
    const float* bhh    = (const float*)d_in[14];
    const float* Wf1    = (const float*)d_in[15];
    const float* bf1    = (const float*)d_in[16];
    const float* Wf2    = (const float*)d_in[17];
    const float* bf2    = (const float*)d_in[18];
    float* out = (float*)d_out;

    const int N  = in_sizes[0] / IN_F;   // 50000
    const int E  = in_sizes[1] / 2;      // 800000
    const int ET = E + N;                // with self-loops
    const int* srcs = eidx;
    const int* dsts = eidx + E;

    // workspace layout
    float* h1   = (float*)d_ws;                    // N*256
    float* g1   = h1 + (size_t)N * 256;            // N*256
    float* as1  = g1 + (size_t)N * 256;            // N*4
    float* ad1  = as1 + (size_t)N * 4;             // N*4
    int* cnt    = (int*)(ad1 + (size_t)N * 4);     // N
    int* rowp   = cnt + N;                         // N+1
    int* cursor = rowp + N + 1;                    // N
    int* eid    = cursor + N;                      // ET
    // layer-2 / LSTM aliases (h1 dead after layer-1 aggregation)
    float* h2 = h1;                                // N*64
    float* g2 = h1 + (size_t)N * 64;               // N*64
    float* tt = h1 + (size_t)N * 128;              // N*32
    float* as2 = as1; float* ad2 = ad1;

    dim3 blk(256);

    // ---- CSR build (shared by both GAT layers) ----
    hipMemsetAsync(cnt, 0, (size_t)N * sizeof(int), stream);
    hipMemsetAsync(cursor, 0, (size_t)N * sizeof(int), stream);
    count_deg<<<(ET + 255) / 256, blk, 0, stream>>>(dsts, E, ET, cnt);
    scan_kernel<<<1, 1024, 0, stream>>>(cnt, rowp, N);
    scatter_edges<<<(ET + 255) / 256, blk, 0, stream>>>(dsts, E, ET, rowp, cursor, eid);

    // ---- GAT layer 1 ----
    gemm_kernel<128, 256, 16><<<(N + 15) / 16, blk, 0, stream>>>(x, W1, h1, N);
    att_scores<<<(N * 4 + 255) / 256, blk, 0, stream>>>(h1, att_s1, att_d1, as1, ad1, N * 4, 3);
    gat_agg_fused<4><<<N, blk, 0, stream>>>(srcs, E, rowp, eid, as1, ad1, h1, bias1, g1, N, 1);

    // ---- GAT layer 2 ----
    gemm_kernel<256, 64, 16><<<(N + 15) / 16, blk, 0, stream>>>(g1, W2, h2, N);
    att_scores<<<(N + 255) / 256, blk, 0, stream>>>(h2, att_s2, att_d2, as2, ad2, N, 0);
    gat_agg_fused<1><<<(N + 3) / 4, blk, 0, stream>>>(srcs, E, rowp, eid, as2, ad2, h2, bias2, g2, N, 0);

    // ---- LSTM ----
    lstm_kernel<<<(N + NPB - 1) / NPB, blk, 0, stream>>>(seq, Wih, Whh, bih, bhh, tt, N);

    // ---- fusion MLP ----
    fusion_kernel<<<512, blk, 0, stream>>>(g2, tt, Wf1, bf1, Wf2, bf2, out, N);
}